// Round 8
// baseline (872.333 us; speedup 1.0000x reference)
//
#include <hip/hip_runtime.h>
#include <hip/hip_bf16.h>

#define Bn 32
#define Ln 2048
#define Dn 768
#define Hn 512
#define Mn (Bn*Ln)
#define EPSC 1e-5f

// ws float-offset layout
#define OFF_CNT  0          // [32] per-batch counts
#define OFF_PH   64         // [32*512] pooled sums (atomic, zeroed)
#define OFF_GSUM 16448      // [512] channel sum   (atomic from statreduce, zeroed)
#define OFF_GSQ  16960      // [512] channel sqsum
// byte offsets
#define OFF_W1TT_BYTES 131072      // bf16 W1tt [24 ktiles][512 n][32 k] = 768 KB
#define OFF_SCR_BYTES  1048576     // f32 scratch [2048 by][1024] = 8 MB
#define OFF_H_BYTES    (16*1048576) // tiled bf16 h, 64 MB

typedef __attribute__((ext_vector_type(8))) short bf16x8;
typedef __attribute__((ext_vector_type(4))) float f32x4;

static __device__ __forceinline__ unsigned short f2bf(float x) {
  __hip_bfloat16 h = __float2bfloat16(x);
  return *reinterpret_cast<unsigned short*>(&h);
}
static __device__ __forceinline__ unsigned int pk2(float lo, float hi) {
  return (unsigned int)f2bf(lo) | ((unsigned int)f2bf(hi) << 16);
}
static __device__ __forceinline__ float bf2f(unsigned short u) {
  return __uint_as_float(((unsigned int)u) << 16);
}
// LDS chunk swizzle: rows 0..7 hit 8 distinct bank groups -> ~2-way max
static __device__ __forceinline__ int swz(int r) { return (r + (r >> 2)) & 3; }

// blocks 0..31: per-batch count; block 32: zero PH+GSUM+GSQ; 33..128: W1 tile.
__global__ __launch_bounds__(256) void prep_kernel(
    const int* __restrict__ mask, const float* __restrict__ W1,
    float* __restrict__ ws, unsigned short* __restrict__ W1tt) {
  int blk = blockIdx.x, t = threadIdx.x;
  if (blk < Bn) {
    __shared__ int red[256];
    int s = 0;
#pragma unroll
    for (int i = 0; i < 8; i++) s += mask[blk * Ln + i * 256 + t];
    red[t] = s;
    __syncthreads();
    for (int off = 128; off > 0; off >>= 1) {
      if (t < off) red[t] += red[t + off];
      __syncthreads();
    }
    if (t == 0) ws[OFF_CNT + blk] = (float)red[0];
  } else if (blk == Bn) {
#pragma unroll
    for (int i = 0; i < 64; i++) ws[OFF_PH + i * 256 + t] = 0.f;
#pragma unroll
    for (int i = 0; i < 4; i++) ws[OFF_GSUM + i * 256 + t] = 0.f;
  } else {
    // W1 [768][512] fp32 -> W1tt[kt][n][k&31] bf16 (24 tiles of 32 KB)
    int idx = blk - Bn - 1;          // 0..95
    int kt = idx % 24;
    int n0 = (idx / 24) * 128;       // 4 n-groups
    int n = n0 + (t & 127);
    int kh = t >> 7;                 // 0..1
#pragma unroll
    for (int i = 0; i < 16; i++) {
      int kk = i * 2 + kh;
      W1tt[kt * 16384 + n * 32 + kk] =
          f2bf(W1[(size_t)(kt * 32 + kk) * Hn + n]);
    }
  }
}

// GEMM1: h = A @ W1 + b1, bf16 MFMA. Block = 32M x 512N (FULL N: A read once
// from HBM by exactly one block -> no inter-block A reuse needed; B is 0.75 MB
// and L2-resident). BK=32, 256 thr = 4 waves of 32Mx128N, acc 2x8 (64 AGPR).
// LDS ~35 KB, launch_bounds(256,3) -> 3 barrier domains/CU.
// Stats: per-block 1024 partials written NON-atomically to scratch[by][1024]
// (R6 proved >1M global atomics = write storm); statreduce sums them.
// Hout per block: 32 KB contiguous: by*16384 + w*4096 + (mt*8+nt)*256 + lane*4.
__global__ __launch_bounds__(256, 3) void gemm1_mfma(
    const float* __restrict__ A, const unsigned short* __restrict__ W1tt,
    const float* __restrict__ b1, const int* __restrict__ mask,
    unsigned short* __restrict__ Hout, float* __restrict__ scratch)
{
  __shared__ unsigned short As[32 * 32];    // [m][32k] swizzled, 2 KB
  __shared__ unsigned short Bs[512 * 32];   // [n][32k] swizzled, 32 KB

  const int t = threadIdx.x;
  const int by = blockIdx.x;       // 0..2047
  const int bm0 = by * 32;
  const int w = t >> 6;
  const int lane = t & 63;
  const int l15 = lane & 15;
  const int quad = lane >> 4;
  const int wn0 = w * 128;

  // A staging: thread -> row t>>3 (0..31), k-seg t&7 (4 fp32)
  const int arow = t >> 3, aseg = t & 7;
  const float* Ap = A + (size_t)(bm0 + arow) * Dn + aseg * 4;
  unsigned short* Asw =
      &As[arow * 32 + (((aseg >> 1) ^ swz(arow)) << 3) + (aseg & 1) * 4];

  // B staging: thread copies rows t and t+256 (64 B each, coalesced)
  const int br0 = t, br1 = t + 256;
  const int sw0 = swz(br0), sw1 = swz(br1);

  f32x4 acc[2][8];
#pragma unroll
  for (int i = 0; i < 2; i++)
#pragma unroll
    for (int j = 0; j < 8; j++) acc[i][j] = (f32x4){0.f, 0.f, 0.f, 0.f};

  for (int kt = 0; kt < 24; kt++) {
    float4 av = *(const float4*)(Ap + kt * 32);
    const unsigned short* Bg = W1tt + kt * 16384;
    uint4 bv[8];
#pragma unroll
    for (int c = 0; c < 4; c++) {
      bv[c] = *(const uint4*)(Bg + br0 * 32 + c * 8);
      bv[4 + c] = *(const uint4*)(Bg + br1 * 32 + c * 8);
    }
    __syncthreads();
    uint2 pa;
    pa.x = pk2(av.x, av.y);
    pa.y = pk2(av.z, av.w);
    *(uint2*)Asw = pa;
#pragma unroll
    for (int c = 0; c < 4; c++) {
      *(uint4*)&Bs[br0 * 32 + ((c ^ sw0) << 3)] = bv[c];
      *(uint4*)&Bs[br1 * 32 + ((c ^ sw1) << 3)] = bv[4 + c];
    }
    __syncthreads();

    bf16x8 af[2];
#pragma unroll
    for (int mt = 0; mt < 2; mt++) {
      const int r = mt * 16 + l15;
      af[mt] = *(const bf16x8*)&As[r * 32 + ((quad ^ swz(r)) << 3)];
    }
#pragma unroll
    for (int nt = 0; nt < 8; nt++) {
      const int r = wn0 + nt * 16 + l15;
      bf16x8 bf = *(const bf16x8*)&Bs[r * 32 + ((quad ^ swz(r)) << 3)];
      acc[0][nt] = __builtin_amdgcn_mfma_f32_16x16x32_bf16(af[0], bf, acc[0][nt], 0, 0, 0);
      acc[1][nt] = __builtin_amdgcn_mfma_f32_16x16x32_bf16(af[1], bf, acc[1][nt], 0, 0, 0);
    }
  }

  // ---- epilogue: bias, masked stats (quad-shuffle reduced, non-atomic
  // scratch store), coalesced tiled bf16 store ----
  float mk[2][4];
#pragma unroll
  for (int mt = 0; mt < 2; mt++) {
    int4 mv = *(const int4*)(mask + bm0 + mt * 16 + quad * 4);
    mk[mt][0] = (float)mv.x; mk[mt][1] = (float)mv.y;
    mk[mt][2] = (float)mv.z; mk[mt][3] = (float)mv.w;
  }

  float* sblk = scratch + (size_t)by * 1024;
  const size_t cbase = (size_t)by * 16384 + (size_t)w * 4096;
#pragma unroll
  for (int nt = 0; nt < 8; nt++) {
    const int nl = wn0 + nt * 16 + l15;
    const float bias = b1[nl];
    float ps = 0.f, pq = 0.f;
#pragma unroll
    for (int mt = 0; mt < 2; mt++) {
      ushort4 st;
      float v0 = acc[mt][nt][0] + bias;
      float v1 = acc[mt][nt][1] + bias;
      float v2 = acc[mt][nt][2] + bias;
      float v3 = acc[mt][nt][3] + bias;
      ps += v0 * mk[mt][0] + v1 * mk[mt][1] + v2 * mk[mt][2] + v3 * mk[mt][3];
      pq += v0 * v0 * mk[mt][0] + v1 * v1 * mk[mt][1] +
            v2 * v2 * mk[mt][2] + v3 * v3 * mk[mt][3];
      st.x = f2bf(v0); st.y = f2bf(v1); st.z = f2bf(v2); st.w = f2bf(v3);
      *(ushort4*)&Hout[cbase + (size_t)(mt * 8 + nt) * 256 + lane * 4] = st;
    }
    ps += __shfl_xor(ps, 16); ps += __shfl_xor(ps, 32);
    pq += __shfl_xor(pq, 16); pq += __shfl_xor(pq, 32);
    if (quad == 0) {
      sblk[nl] = ps;
      sblk[512 + nl] = pq;
    }
  }
}

// Deterministic stat reduction: grid (4 colgroups x 16 bygroups).
__global__ __launch_bounds__(256) void statreduce(
    const float* __restrict__ scratch, float* __restrict__ ws) {
  int col = blockIdx.x * 256 + threadIdx.x;   // 0..1023
  int by0 = blockIdx.y * 128;
  float s0 = 0.f, s1 = 0.f, s2 = 0.f, s3 = 0.f;
  for (int by = by0; by < by0 + 128; by += 4) {
    s0 += scratch[(size_t)by * 1024 + col];
    s1 += scratch[(size_t)(by + 1) * 1024 + col];
    s2 += scratch[(size_t)(by + 2) * 1024 + col];
    s3 += scratch[(size_t)(by + 3) * 1024 + col];
  }
  float s = (s0 + s1) + (s2 + s3);
  atomicAdd(&ws[OFF_GSUM + col], s);   // GSQ is contiguous after GSUM
}

// BN(finalize fused) + ReLU + masked pool. Block g handles 4 gemm chunks
// (128 m-rows); thread owns 2 channels; register acc; 0.26M atomics total.
__global__ __launch_bounds__(256) void bnpool_kernel(
    const unsigned short* __restrict__ Hbuf, const int* __restrict__ mask,
    const float* __restrict__ ws, const float* __restrict__ gamma,
    const float* __restrict__ beta, float* __restrict__ PH)
{
  __shared__ float mkf[128];
  __shared__ float redc[32];
  const int t = threadIdx.x;
  const int g = blockIdx.x;      // 0..511
  const int b = g >> 4;          // 16 blocks per batch
  if (t < 32) redc[t] = ws[OFF_CNT + t];
  if (t < 128) mkf[t] = (float)mask[g * 128 + t];
  __syncthreads();

  float nv = 0.f;
#pragma unroll
  for (int i = 0; i < 32; i++) nv += redc[i];
  nv = fmaxf(nv, 1.f);
  const float inv = 1.f / nv;

  const int wlo = t >> 7, ntq = (t >> 4) & 7, l15 = t & 15;
#pragma unroll
  for (int h = 0; h < 2; h++) {
    const int wv = h * 2 + wlo;
    const int c = wv * 128 + ntq * 16 + l15;
    const float m = ws[OFF_GSUM + c] * inv;
    const float var = ws[OFF_GSQ + c] * inv - m * m;
    const float istd = rsqrtf(fmaxf(var, 0.f) + EPSC);
    const float scv = istd * gamma[c];
    const float shv = beta[c] - m * scv;
    float acc = 0.f;
#pragma unroll
    for (int j = 0; j < 4; j++) {
      const size_t base = (size_t)(g * 4 + j) * 16384 + (size_t)wv * 4096;
#pragma unroll
      for (int mt = 0; mt < 2; mt++)
#pragma unroll
        for (int q = 0; q < 4; q++) {
          ushort4 hv = *(const ushort4*)&Hbuf[base + (mt * 8 + ntq) * 256 +
                                              (q * 16 + l15) * 4];
          const float* mv = &mkf[j * 32 + mt * 16 + q * 4];
          acc += fmaxf(fmaf(bf2f(hv.x), scv, shv), 0.f) * mv[0]
               + fmaxf(fmaf(bf2f(hv.y), scv, shv), 0.f) * mv[1]
               + fmaxf(fmaf(bf2f(hv.z), scv, shv), 0.f) * mv[2]
               + fmaxf(fmaf(bf2f(hv.w), scv, shv), 0.f) * mv[3];
        }
    }
    atomicAdd(&PH[b * Hn + c], acc);
  }
}

// out[b][c] = (PH[b]/max(cnt,1)) @ W2[:,c] + b2[c]*(cnt/max(cnt,1))
__global__ __launch_bounds__(128) void final_kernel(
    const float* __restrict__ pooledh, const float* __restrict__ cnt,
    const float* __restrict__ W2, const float* __restrict__ b2,
    float* __restrict__ out)
{
  __shared__ float pr[Hn];
  int b = blockIdx.x >> 2;
  int cc = blockIdx.x & 3;
  int t = threadIdx.x;
  float nb = cnt[b];
  float inv = 1.f / fmaxf(nb, 1.f);
#pragma unroll
  for (int i = 0; i < 4; i++)
    pr[t + i * 128] = pooledh[b * Hn + t + i * 128] * inv;
  __syncthreads();
  int c = cc * 128 + t;
  float a0 = 0.f, a1 = 0.f, a2 = 0.f, a3 = 0.f;
  for (int i = 0; i < Hn; i += 4) {
    a0 = fmaf(pr[i],     W2[(size_t)i * Hn + c],       a0);
    a1 = fmaf(pr[i + 1], W2[(size_t)(i + 1) * Hn + c], a1);
    a2 = fmaf(pr[i + 2], W2[(size_t)(i + 2) * Hn + c], a2);
    a3 = fmaf(pr[i + 3], W2[(size_t)(i + 3) * Hn + c], a3);
  }
  out[b * Hn + c] = (a0 + a1) + (a2 + a3) + b2[c] * (nb * inv);
}

extern "C" void kernel_launch(void* const* d_in, const int* in_sizes, int n_in,
                              void* d_out, int out_size, void* d_ws, size_t ws_size,
                              hipStream_t stream) {
  const float* hidden = (const float*)d_in[0];
  const int*   mask   = (const int*)d_in[1];
  const float* W1     = (const float*)d_in[2];
  const float* b1     = (const float*)d_in[3];
  const float* gamma  = (const float*)d_in[4];
  const float* beta   = (const float*)d_in[5];
  const float* W2     = (const float*)d_in[6];
  const float* b2     = (const float*)d_in[7];
  float* out = (float*)d_out;
  float* ws  = (float*)d_ws;
  unsigned short* W1tt = (unsigned short*)((char*)d_ws + OFF_W1TT_BYTES);
  float* scratch       = (float*)((char*)d_ws + OFF_SCR_BYTES);
  unsigned short* Hbuf = (unsigned short*)((char*)d_ws + OFF_H_BYTES);

  prep_kernel<<<Bn + 1 + 96, 256, 0, stream>>>(mask, W1, ws, W1tt);
  gemm1_mfma<<<Mn / 32, 256, 0, stream>>>(
      hidden, W1tt, b1, mask, Hbuf, scratch);
  statreduce<<<dim3(4, 16), 256, 0, stream>>>(scratch, ws);
  bnpool_kernel<<<512, 256, 0, stream>>>(
      Hbuf, mask, ws, gamma, beta, ws + OFF_PH);
  final_kernel<<<Bn * 4, 128, 0, stream>>>(ws + OFF_PH, ws + OFF_CNT, W2, b2, out);
}